// Round 15
// baseline (136.371 us; speedup 1.0000x reference)
//
#include <hip/hip_runtime.h>
#include <hip/hip_bf16.h>
#include <math.h>
#include <stdint.h>

#define N_TOK 8192
#define DIM   1024
#define FDIM  1024
#define NEXP  8

typedef unsigned short u16;
typedef __bf16 bf16x8 __attribute__((ext_vector_type(8)));
typedef float  f32x4  __attribute__((ext_vector_type(4)));

__device__ __forceinline__ u16 f2bf(float f) {
  union { float f; uint32_t u; } v; v.f = f;
  return (u16)((v.u + 0x7fffu + ((v.u >> 16) & 1u)) >> 16);
}

// tanh-form GELU via hardware exp; |tanh-arg| clamped for stability.
__device__ __forceinline__ float gelu_fast(float v) {
  float y = 0.7978845608028654f * (v + 0.044715f * v * v * v);
  y = fminf(fmaxf(y, -9.0f), 9.0f);
  float ex = __expf(2.0f * y);            // v_exp_f32
  float t = 1.0f - 2.0f / (ex + 1.0f);    // tanh(y)
  return 0.5f * v * (1.0f + t);
}

// ---------------- fused prep: router + We transpose, INTERLEAVED by block parity ----------------
// (b&1)==0 -> router block (idx 0..2047), (b&1)==1 -> transpose block (idx 0..2047).
// Parity interleave puts both block types on every CU from dispatch start, so the
// router's VALU/fp64 work overlaps the transpose's BW work instead of serializing.
__global__ __launch_bounds__(256) void k_prep(
    const float* __restrict__ x, const float* __restrict__ Wr,
    const float* __restrict__ br, const float* __restrict__ We,
    u16* __restrict__ xb, u16* __restrict__ WeT,
    int* __restrict__ topk_idx, float* __restrict__ topk_w0,
    int* __restrict__ gcount) {
  __shared__ float tile[64][65];
  int b = blockIdx.x;
  if (b == 0 && threadIdx.x < NEXP) gcount[threadIdx.x] = 0; // replaces memset dispatch
  int idx = b >> 1;
  if ((b & 1) == 0) {
    // ---- router + x->bf16 convert: 4 tokens/block, one wave each (fp64 accum) ----
    int n = idx * 4 + (threadIdx.x >> 6);
    int lane = threadIdx.x & 63;
    const float4* xr = (const float4*)(x + (size_t)n * DIM);
    ushort4* xbr = (ushort4*)(xb + (size_t)n * DIM);
    double acc[8];
#pragma unroll
    for (int e = 0; e < 8; ++e) acc[e] = 0.0;
#pragma unroll
    for (int i = 0; i < 4; ++i) {
      int d4 = lane + 64 * i;
      float4 v = xr[d4];
      ushort4 o;
      o.x = f2bf(v.x); o.y = f2bf(v.y); o.z = f2bf(v.z); o.w = f2bf(v.w);
      xbr[d4] = o;
      float vv[4] = {v.x, v.y, v.z, v.w};
      const float* wr = Wr + (size_t)d4 * 4 * NEXP;
#pragma unroll
      for (int j = 0; j < 4; ++j) {
        float4 w0 = *(const float4*)(wr + j * 8);
        float4 w1 = *(const float4*)(wr + j * 8 + 4);
        acc[0] += (double)vv[j] * w0.x; acc[1] += (double)vv[j] * w0.y;
        acc[2] += (double)vv[j] * w0.z; acc[3] += (double)vv[j] * w0.w;
        acc[4] += (double)vv[j] * w1.x; acc[5] += (double)vv[j] * w1.y;
        acc[6] += (double)vv[j] * w1.z; acc[7] += (double)vv[j] * w1.w;
      }
    }
#pragma unroll
    for (int e = 0; e < 8; ++e) {
      for (int off = 32; off; off >>= 1) acc[e] += __shfl_xor(acc[e], off);
    }
    if (lane == 0) {
      double lg[8];
#pragma unroll
      for (int e = 0; e < 8; ++e) lg[e] = acc[e] + (double)br[e];
      int i0 = 0; double v0 = lg[0];
#pragma unroll
      for (int e = 1; e < 8; ++e) if (lg[e] > v0) { v0 = lg[e]; i0 = e; }
      int i1 = -1; double v1 = -1e300;
#pragma unroll
      for (int e = 0; e < 8; ++e) if (e != i0 && lg[e] > v1) { v1 = lg[e]; i1 = e; }
      float w0 = 1.0f / (1.0f + expf((float)(v1 - v0)));
      topk_idx[n] = i0 | (i1 << 8);
      topk_w0[n] = w0;
    }
  } else {
    // ---- We [e][d][f] fp32 -> WeT [e][f][d] bf16, 64x64 tiles ----
    int e = idx >> 8;
    int d0 = ((idx >> 4) & 15) * 64, f0 = (idx & 15) * 64;
    int t = threadIdx.x;
    {
      int rr = t >> 4, c4 = (t & 15) * 4;   // float4 reads, 16 rows per pass
      const float* src = We + (size_t)e * DIM * FDIM + (size_t)d0 * FDIM + f0;
#pragma unroll
      for (int i = 0; i < 4; ++i) {
        float4 v = *(const float4*)(src + (size_t)(i * 16 + rr) * FDIM + c4);
        tile[i * 16 + rr][c4 + 0] = v.x;
        tile[i * 16 + rr][c4 + 1] = v.y;
        tile[i * 16 + rr][c4 + 2] = v.z;
        tile[i * 16 + rr][c4 + 3] = v.w;
      }
    }
    __syncthreads();
    // write: thread (dl8 = t&7, fr = t>>3) -> 2x ushort8 stores (16B aligned)
    int dl8 = t & 7, fr = t >> 3;   // fr in 0..31
    u16* dst = WeT + (size_t)e * FDIM * DIM + (size_t)f0 * DIM + d0;
#pragma unroll
    for (int i = 0; i < 2; ++i) {
      int fl = i * 32 + fr;
      union { u16 us[8]; uint4 q; } o;
#pragma unroll
      for (int j = 0; j < 8; ++j) o.us[j] = f2bf(tile[dl8 * 8 + j][fl]);
      *(uint4*)(dst + (size_t)fl * DIM + dl8 * 8) = o.q;
    }
  }
}

// ---------------- build per-expert token lists (entries carry n*2 + choice_k) ----------------
__global__ __launch_bounds__(256) void k_build_lists(const int* __restrict__ topk_idx,
                                                     int* __restrict__ gcount,
                                                     int* __restrict__ token_list) {
  __shared__ int lcount[8];
  __shared__ int lbase[8];
  int t = threadIdx.x;
  int n = blockIdx.x * 256 + t;
  if (t < 8) lcount[t] = 0;
  __syncthreads();
  int pk = topk_idx[n];
  int e0 = pk & 0xff, e1 = (pk >> 8) & 0xff;
  int p0 = atomicAdd(&lcount[e0], 1);
  int p1 = atomicAdd(&lcount[e1], 1);
  __syncthreads();
  if (t < 8) lbase[t] = atomicAdd(&gcount[t], lcount[t]);
  __syncthreads();
  token_list[e0 * N_TOK + lbase[e0] + p0] = n * 2;      // choice 0
  token_list[e1 * N_TOK + lbase[e1] + p1] = n * 2 + 1;  // choice 1
}

// ---------------- gathered expert GEMM -> RAW h (bf16) scratch hbuf[2n+k][f] ----------------
// FROZEN round-11 structure (best measured: 52.2us).
#define BM 128
#define BN 128
#define BK 64
#define NWG 1088

__global__ __launch_bounds__(256, 2) void k_moe_gemm(
    const u16* __restrict__ xb, const u16* __restrict__ WeT,
    const int* __restrict__ gcount, const int* __restrict__ token_list,
    u16* __restrict__ hbuf) {
  int b = blockIdx.x;
  int w = (b & 7) * (NWG / 8) + (b >> 3);  // bijective XCD swizzle (1088 = 8*136)
  int e = -1, my = 0, fx = 0, cnt = 0, pfx = 0;
#pragma unroll
  for (int i = 0; i < NEXP; ++i) {
    int c = gcount[i];
    int tiles = ((c + BM - 1) >> 7) * (FDIM / BN);
    if (e < 0 && w < pfx + tiles) {
      e = i; int lw = w - pfx; my = lw >> 3; fx = lw & 7; cnt = c;
    }
    pfx += tiles;
  }
  if (e < 0) return;
  int m0 = my * BM, f0 = fx * BN;

  __shared__ u16 sA[BM * BK]; // 16KB: [row][64], src pre-swizzled by (row&7)
  __shared__ u16 sB[BN * BK]; // 16KB

  int tid = threadIdx.x;
  int lane = tid & 63, wid = tid >> 6;
  int wm = wid >> 1, wn = wid & 1;
  int rA = lane & 15, kg = lane >> 4;

  const int* tl = token_list + e * N_TOK;

  const u16* aA[4];
  const u16* aB[4];
  int cnt1 = cnt - 1;
#pragma unroll
  for (int it = 0; it < 4; ++it) {
    int c = it * 256 + tid;
    int row = c >> 3, cj = c & 7;
    int sw = (cj * 8) ^ ((row & 7) << 3); // element offset in 64-elem k-window (XOR swizzle)
    int slot = m0 + row; if (slot > cnt1) slot = cnt1;
    int tok = tl[slot] >> 1;
    aA[it] = xb + (size_t)tok * DIM + sw;
    aB[it] = WeT + ((size_t)(e * FDIM + f0 + row)) * DIM + sw;
  }

  f32x4 zero = {0.f, 0.f, 0.f, 0.f};
  f32x4 acc[4][4];
#pragma unroll
  for (int mi = 0; mi < 4; ++mi)
#pragma unroll
    for (int ni = 0; ni < 4; ++ni) acc[mi][ni] = zero;

  const char* pA = (const char*)sA + (wm * 64 + rA) * 128;
  const char* pB = (const char*)sB + (wn * 64 + rA) * 128;
  int swz = (rA & 7) << 4;

  for (int kt = 0; kt < DIM / BK; ++kt) {
    int k0 = kt * BK;
#pragma unroll
    for (int it = 0; it < 4; ++it) {
      __builtin_amdgcn_global_load_lds(
          (const __attribute__((address_space(1))) void*)(aA[it] + k0),
          (__attribute__((address_space(3))) void*)(sA + (it * 256 + tid) * 8), 16, 0, 0);
      __builtin_amdgcn_global_load_lds(
          (const __attribute__((address_space(1))) void*)(aB[it] + k0),
          (__attribute__((address_space(3))) void*)(sB + (it * 256 + tid) * 8), 16, 0, 0);
    }
    __syncthreads(); // drains vmcnt -> LDS valid
#pragma unroll
    for (int kk = 0; kk < 2; ++kk) {
      int kb = ((kk << 6) | (kg << 4)) ^ swz;
      bf16x8 av[4], bv[4];
#pragma unroll
      for (int mi = 0; mi < 4; ++mi)
        av[mi] = *(const bf16x8*)(pA + mi * 2048 + kb);
#pragma unroll
      for (int ni = 0; ni < 4; ++ni)
        bv[ni] = *(const bf16x8*)(pB + ni * 2048 + kb);
#pragma unroll
      for (int mi = 0; mi < 4; ++mi)
#pragma unroll
        for (int ni = 0; ni < 4; ++ni)
          acc[mi][ni] = __builtin_amdgcn_mfma_f32_16x16x32_bf16(av[mi], bv[ni], acc[mi][ni], 0, 0, 0);
    }
    __syncthreads(); // all reads done before next stage overwrites
  }

  // epilogue: raw h -> bf16 plain stores (bias+GELU deferred to k_combine)
#pragma unroll
  for (int mi = 0; mi < 4; ++mi) {
#pragma unroll
    for (int j = 0; j < 4; ++j) {
      int slot = m0 + wm * 64 + mi * 16 + kg * 4 + j;
      if (slot < cnt) {
        int tok2 = tl[slot]; // n*2+k
        u16* hrow = hbuf + (size_t)tok2 * FDIM;
        int colf = f0 + wn * 64 + rA;
#pragma unroll
        for (int ni = 0; ni < 4; ++ni)
          hrow[colf + ni * 16] = f2bf(acc[mi][ni][j]);
      }
    }
  }
}

// ---------------- combine: out[n] = w0*gelu(h0+be[e0]) + w1*gelu(h1+be[e1]) ----------------
__global__ __launch_bounds__(256) void k_combine(const u16* __restrict__ hbuf,
                                                 const int* __restrict__ topk_idx,
                                                 const float* __restrict__ topk_w0,
                                                 const float* __restrict__ be,
                                                 float* __restrict__ out) {
  int n = blockIdx.x * 2 + (threadIdx.x >> 7);
  int t = threadIdx.x & 127;
  int pk = topk_idx[n];
  int e0 = pk & 0xff, e1 = (pk >> 8) & 0xff;
  float w0 = topk_w0[n], w1 = 1.0f - w0;
  const bf16x8* r0 = (const bf16x8*)(hbuf + (size_t)(2 * n) * FDIM);
  const bf16x8* r1 = (const bf16x8*)(hbuf + (size_t)(2 * n + 1) * FDIM);
  bf16x8 a = r0[t], c = r1[t];
  const float* b0 = be + e0 * FDIM + t * 8;  // be: 32KB, L1/L2-resident
  const float* b1 = be + e1 * FDIM + t * 8;
  float4 b0a = *(const float4*)(b0), b0b = *(const float4*)(b0 + 4);
  float4 b1a = *(const float4*)(b1), b1b = *(const float4*)(b1 + 4);
  float bb0[8] = {b0a.x, b0a.y, b0a.z, b0a.w, b0b.x, b0b.y, b0b.z, b0b.w};
  float bb1[8] = {b1a.x, b1a.y, b1a.z, b1a.w, b1b.x, b1b.y, b1b.z, b1b.w};
  float o[8];
#pragma unroll
  for (int i = 0; i < 8; ++i) {
    float v0 = (float)a[i] + bb0[i];
    float v1 = (float)c[i] + bb1[i];
    o[i] = w0 * gelu_fast(v0) + w1 * gelu_fast(v1);
  }
  float* orow = out + (size_t)n * FDIM + t * 8;
  *(float4*)(orow)     = *(float4*)(o);
  *(float4*)(orow + 4) = *(float4*)(o + 4);
}

extern "C" void kernel_launch(void* const* d_in, const int* in_sizes, int n_in,
                              void* d_out, int out_size, void* d_ws, size_t ws_size,
                              hipStream_t stream) {
  const float* x  = (const float*)d_in[0];
  const float* Wr = (const float*)d_in[1];
  const float* br = (const float*)d_in[2];
  const float* We = (const float*)d_in[3];
  const float* be = (const float*)d_in[4];
  float* out = (float*)d_out;

  char* ws = (char*)d_ws;
  u16* xb = (u16*)ws;                ws += (size_t)N_TOK * DIM * 2;
  u16* WeT = (u16*)ws;               ws += (size_t)NEXP * FDIM * DIM * 2;
  u16* hbuf = (u16*)ws;              ws += (size_t)2 * N_TOK * FDIM * 2;
  int* token_list = (int*)ws;        ws += (size_t)NEXP * N_TOK * 4;
  int* topk_idx = (int*)ws;          ws += (size_t)N_TOK * 4;
  float* topk_w0 = (float*)ws;       ws += (size_t)N_TOK * 4;
  int* gcount = (int*)ws;

  k_prep<<<dim3(4096), dim3(256), 0, stream>>>(x, Wr, br, We, xb, WeT, topk_idx, topk_w0, gcount);
  k_build_lists<<<dim3(N_TOK / 256), dim3(256), 0, stream>>>(topk_idx, gcount, token_list);
  // worst-case tile count: sum_e ceil(cnt_e/128)*8 <= (128+8)*8 = 1088
  k_moe_gemm<<<dim3(NWG), dim3(256), 0, stream>>>(xb, WeT, gcount, token_list, hbuf);
  k_combine<<<dim3(N_TOK / 2), dim3(256), 0, stream>>>(hbuf, topk_idx, topk_w0, be, out);
}

// Round 16
// 111.841 us; speedup vs baseline: 1.2193x; 1.2193x over previous
//
#include <hip/hip_runtime.h>
#include <hip/hip_bf16.h>
#include <math.h>
#include <stdint.h>

#define N_TOK 8192
#define DIM   1024
#define FDIM  1024
#define NEXP  8

typedef unsigned short u16;
typedef __bf16 bf16x8 __attribute__((ext_vector_type(8)));
typedef float  f32x4  __attribute__((ext_vector_type(4)));

__device__ __forceinline__ u16 f2bf(float f) {
  union { float f; uint32_t u; } v; v.f = f;
  return (u16)((v.u + 0x7fffu + ((v.u >> 16) & 1u)) >> 16);
}

// tanh-form GELU via hardware exp; |tanh-arg| clamped for stability.
__device__ __forceinline__ float gelu_fast(float v) {
  float y = 0.7978845608028654f * (v + 0.044715f * v * v * v);
  y = fminf(fmaxf(y, -9.0f), 9.0f);
  float ex = __expf(2.0f * y);            // v_exp_f32
  float t = 1.0f - 2.0f / (ex + 1.0f);    // tanh(y)
  return 0.5f * v * (1.0f + t);
}

// ---------------- fused prep: router (blocks 0..2047) + We transpose (blocks 2048..4095) ----------------
// ORDERED split is the measured optimum: router fills the machine first, transpose
// backfills. Parity interleave (r15) regressed 2.5x: mixed-type residency starves
// both phases of same-type TLP.
__global__ __launch_bounds__(256) void k_prep(
    const float* __restrict__ x, const float* __restrict__ Wr,
    const float* __restrict__ br, const float* __restrict__ We,
    u16* __restrict__ xb, u16* __restrict__ WeT,
    int* __restrict__ topk_idx, float* __restrict__ topk_w0,
    int* __restrict__ gcount) {
  __shared__ float tile[64][65];
  int b = blockIdx.x;
  if (b == 0 && threadIdx.x < NEXP) gcount[threadIdx.x] = 0; // replaces memset dispatch
  if (b < 2048) {
    // ---- router + x->bf16 convert: 4 tokens/block, one wave each (fp64 accum) ----
    int n = b * 4 + (threadIdx.x >> 6);
    int lane = threadIdx.x & 63;
    const float4* xr = (const float4*)(x + (size_t)n * DIM);
    ushort4* xbr = (ushort4*)(xb + (size_t)n * DIM);
    double acc[8];
#pragma unroll
    for (int e = 0; e < 8; ++e) acc[e] = 0.0;
#pragma unroll
    for (int i = 0; i < 4; ++i) {
      int d4 = lane + 64 * i;
      float4 v = xr[d4];
      ushort4 o;
      o.x = f2bf(v.x); o.y = f2bf(v.y); o.z = f2bf(v.z); o.w = f2bf(v.w);
      xbr[d4] = o;
      float vv[4] = {v.x, v.y, v.z, v.w};
      const float* wr = Wr + (size_t)d4 * 4 * NEXP;
#pragma unroll
      for (int j = 0; j < 4; ++j) {
        float4 w0 = *(const float4*)(wr + j * 8);
        float4 w1 = *(const float4*)(wr + j * 8 + 4);
        acc[0] += (double)vv[j] * w0.x; acc[1] += (double)vv[j] * w0.y;
        acc[2] += (double)vv[j] * w0.z; acc[3] += (double)vv[j] * w0.w;
        acc[4] += (double)vv[j] * w1.x; acc[5] += (double)vv[j] * w1.y;
        acc[6] += (double)vv[j] * w1.z; acc[7] += (double)vv[j] * w1.w;
      }
    }
#pragma unroll
    for (int e = 0; e < 8; ++e) {
      for (int off = 32; off; off >>= 1) acc[e] += __shfl_xor(acc[e], off);
    }
    if (lane == 0) {
      double lg[8];
#pragma unroll
      for (int e = 0; e < 8; ++e) lg[e] = acc[e] + (double)br[e];
      int i0 = 0; double v0 = lg[0];
#pragma unroll
      for (int e = 1; e < 8; ++e) if (lg[e] > v0) { v0 = lg[e]; i0 = e; }
      int i1 = -1; double v1 = -1e300;
#pragma unroll
      for (int e = 0; e < 8; ++e) if (e != i0 && lg[e] > v1) { v1 = lg[e]; i1 = e; }
      float w0 = 1.0f / (1.0f + expf((float)(v1 - v0)));
      topk_idx[n] = i0 | (i1 << 8);
      topk_w0[n] = w0;
    }
  } else {
    // ---- We [e][d][f] fp32 -> WeT [e][f][d] bf16, 64x64 tiles ----
    int tb = b - 2048;
    int e = tb >> 8;
    int d0 = ((tb >> 4) & 15) * 64, f0 = (tb & 15) * 64;
    int t = threadIdx.x;
    {
      int rr = t >> 4, c4 = (t & 15) * 4;   // float4 reads, 16 rows per pass
      const float* src = We + (size_t)e * DIM * FDIM + (size_t)d0 * FDIM + f0;
#pragma unroll
      for (int i = 0; i < 4; ++i) {
        float4 v = *(const float4*)(src + (size_t)(i * 16 + rr) * FDIM + c4);
        tile[i * 16 + rr][c4 + 0] = v.x;
        tile[i * 16 + rr][c4 + 1] = v.y;
        tile[i * 16 + rr][c4 + 2] = v.z;
        tile[i * 16 + rr][c4 + 3] = v.w;
      }
    }
    __syncthreads();
    // write: thread (dl8 = t&7, fr = t>>3) -> 2x ushort8 stores (16B aligned)
    int dl8 = t & 7, fr = t >> 3;   // fr in 0..31
    u16* dst = WeT + (size_t)e * FDIM * DIM + (size_t)f0 * DIM + d0;
#pragma unroll
    for (int i = 0; i < 2; ++i) {
      int fl = i * 32 + fr;
      union { u16 us[8]; uint4 q; } o;
#pragma unroll
      for (int j = 0; j < 8; ++j) o.us[j] = f2bf(tile[dl8 * 8 + j][fl]);
      *(uint4*)(dst + (size_t)fl * DIM + dl8 * 8) = o.q;
    }
  }
}

// ---------------- build per-expert token lists (entries carry n*2 + choice_k) ----------------
__global__ __launch_bounds__(256) void k_build_lists(const int* __restrict__ topk_idx,
                                                     int* __restrict__ gcount,
                                                     int* __restrict__ token_list) {
  __shared__ int lcount[8];
  __shared__ int lbase[8];
  int t = threadIdx.x;
  int n = blockIdx.x * 256 + t;
  if (t < 8) lcount[t] = 0;
  __syncthreads();
  int pk = topk_idx[n];
  int e0 = pk & 0xff, e1 = (pk >> 8) & 0xff;
  int p0 = atomicAdd(&lcount[e0], 1);
  int p1 = atomicAdd(&lcount[e1], 1);
  __syncthreads();
  if (t < 8) lbase[t] = atomicAdd(&gcount[t], lcount[t]);
  __syncthreads();
  token_list[e0 * N_TOK + lbase[e0] + p0] = n * 2;      // choice 0
  token_list[e1 * N_TOK + lbase[e1] + p1] = n * 2 + 1;  // choice 1
}

// ---------------- gathered expert GEMM -> RAW h (bf16) scratch hbuf[2n+k][f] ----------------
// FROZEN round-11 structure (best measured: 52.2us).
#define BM 128
#define BN 128
#define BK 64
#define NWG 1088

__global__ __launch_bounds__(256, 2) void k_moe_gemm(
    const u16* __restrict__ xb, const u16* __restrict__ WeT,
    const int* __restrict__ gcount, const int* __restrict__ token_list,
    u16* __restrict__ hbuf) {
  int b = blockIdx.x;
  int w = (b & 7) * (NWG / 8) + (b >> 3);  // bijective XCD swizzle (1088 = 8*136)
  int e = -1, my = 0, fx = 0, cnt = 0, pfx = 0;
#pragma unroll
  for (int i = 0; i < NEXP; ++i) {
    int c = gcount[i];
    int tiles = ((c + BM - 1) >> 7) * (FDIM / BN);
    if (e < 0 && w < pfx + tiles) {
      e = i; int lw = w - pfx; my = lw >> 3; fx = lw & 7; cnt = c;
    }
    pfx += tiles;
  }
  if (e < 0) return;
  int m0 = my * BM, f0 = fx * BN;

  __shared__ u16 sA[BM * BK]; // 16KB: [row][64], src pre-swizzled by (row&7)
  __shared__ u16 sB[BN * BK]; // 16KB

  int tid = threadIdx.x;
  int lane = tid & 63, wid = tid >> 6;
  int wm = wid >> 1, wn = wid & 1;
  int rA = lane & 15, kg = lane >> 4;

  const int* tl = token_list + e * N_TOK;

  const u16* aA[4];
  const u16* aB[4];
  int cnt1 = cnt - 1;
#pragma unroll
  for (int it = 0; it < 4; ++it) {
    int c = it * 256 + tid;
    int row = c >> 3, cj = c & 7;
    int sw = (cj * 8) ^ ((row & 7) << 3); // element offset in 64-elem k-window (XOR swizzle)
    int slot = m0 + row; if (slot > cnt1) slot = cnt1;
    int tok = tl[slot] >> 1;
    aA[it] = xb + (size_t)tok * DIM + sw;
    aB[it] = WeT + ((size_t)(e * FDIM + f0 + row)) * DIM + sw;
  }

  f32x4 zero = {0.f, 0.f, 0.f, 0.f};
  f32x4 acc[4][4];
#pragma unroll
  for (int mi = 0; mi < 4; ++mi)
#pragma unroll
    for (int ni = 0; ni < 4; ++ni) acc[mi][ni] = zero;

  const char* pA = (const char*)sA + (wm * 64 + rA) * 128;
  const char* pB = (const char*)sB + (wn * 64 + rA) * 128;
  int swz = (rA & 7) << 4;

  for (int kt = 0; kt < DIM / BK; ++kt) {
    int k0 = kt * BK;
#pragma unroll
    for (int it = 0; it < 4; ++it) {
      __builtin_amdgcn_global_load_lds(
          (const __attribute__((address_space(1))) void*)(aA[it] + k0),
          (__attribute__((address_space(3))) void*)(sA + (it * 256 + tid) * 8), 16, 0, 0);
      __builtin_amdgcn_global_load_lds(
          (const __attribute__((address_space(1))) void*)(aB[it] + k0),
          (__attribute__((address_space(3))) void*)(sB + (it * 256 + tid) * 8), 16, 0, 0);
    }
    __syncthreads(); // drains vmcnt -> LDS valid
#pragma unroll
    for (int kk = 0; kk < 2; ++kk) {
      int kb = ((kk << 6) | (kg << 4)) ^ swz;
      bf16x8 av[4], bv[4];
#pragma unroll
      for (int mi = 0; mi < 4; ++mi)
        av[mi] = *(const bf16x8*)(pA + mi * 2048 + kb);
#pragma unroll
      for (int ni = 0; ni < 4; ++ni)
        bv[ni] = *(const bf16x8*)(pB + ni * 2048 + kb);
#pragma unroll
      for (int mi = 0; mi < 4; ++mi)
#pragma unroll
        for (int ni = 0; ni < 4; ++ni)
          acc[mi][ni] = __builtin_amdgcn_mfma_f32_16x16x32_bf16(av[mi], bv[ni], acc[mi][ni], 0, 0, 0);
    }
    __syncthreads(); // all reads done before next stage overwrites
  }

  // epilogue: raw h -> bf16 plain stores (bias+GELU deferred to k_combine)
#pragma unroll
  for (int mi = 0; mi < 4; ++mi) {
#pragma unroll
    for (int j = 0; j < 4; ++j) {
      int slot = m0 + wm * 64 + mi * 16 + kg * 4 + j;
      if (slot < cnt) {
        int tok2 = tl[slot]; // n*2+k
        u16* hrow = hbuf + (size_t)tok2 * FDIM;
        int colf = f0 + wn * 64 + rA;
#pragma unroll
        for (int ni = 0; ni < 4; ++ni)
          hrow[colf + ni * 16] = f2bf(acc[mi][ni][j]);
      }
    }
  }
}

// ---------------- combine: out[n] = w0*gelu(h0+be[e0]) + w1*gelu(h1+be[e1]) ----------------
__global__ __launch_bounds__(256) void k_combine(const u16* __restrict__ hbuf,
                                                 const int* __restrict__ topk_idx,
                                                 const float* __restrict__ topk_w0,
                                                 const float* __restrict__ be,
                                                 float* __restrict__ out) {
  int n = blockIdx.x * 2 + (threadIdx.x >> 7);
  int t = threadIdx.x & 127;
  int pk = topk_idx[n];
  int e0 = pk & 0xff, e1 = (pk >> 8) & 0xff;
  float w0 = topk_w0[n], w1 = 1.0f - w0;
  const bf16x8* r0 = (const bf16x8*)(hbuf + (size_t)(2 * n) * FDIM);
  const bf16x8* r1 = (const bf16x8*)(hbuf + (size_t)(2 * n + 1) * FDIM);
  bf16x8 a = r0[t], c = r1[t];
  const float* b0 = be + e0 * FDIM + t * 8;  // be: 32KB, L1/L2-resident
  const float* b1 = be + e1 * FDIM + t * 8;
  float4 b0a = *(const float4*)(b0), b0b = *(const float4*)(b0 + 4);
  float4 b1a = *(const float4*)(b1), b1b = *(const float4*)(b1 + 4);
  float bb0[8] = {b0a.x, b0a.y, b0a.z, b0a.w, b0b.x, b0b.y, b0b.z, b0b.w};
  float bb1[8] = {b1a.x, b1a.y, b1a.z, b1a.w, b1b.x, b1b.y, b1b.z, b1b.w};
  float o[8];
#pragma unroll
  for (int i = 0; i < 8; ++i) {
    float v0 = (float)a[i] + bb0[i];
    float v1 = (float)c[i] + bb1[i];
    o[i] = w0 * gelu_fast(v0) + w1 * gelu_fast(v1);
  }
  float* orow = out + (size_t)n * FDIM + t * 8;
  *(float4*)(orow)     = *(float4*)(o);
  *(float4*)(orow + 4) = *(float4*)(o + 4);
}

extern "C" void kernel_launch(void* const* d_in, const int* in_sizes, int n_in,
                              void* d_out, int out_size, void* d_ws, size_t ws_size,
                              hipStream_t stream) {
  const float* x  = (const float*)d_in[0];
  const float* Wr = (const float*)d_in[1];
  const float* br = (const float*)d_in[2];
  const float* We = (const float*)d_in[3];
  const float* be = (const float*)d_in[4];
  float* out = (float*)d_out;

  char* ws = (char*)d_ws;
  u16* xb = (u16*)ws;                ws += (size_t)N_TOK * DIM * 2;
  u16* WeT = (u16*)ws;               ws += (size_t)NEXP * FDIM * DIM * 2;
  u16* hbuf = (u16*)ws;              ws += (size_t)2 * N_TOK * FDIM * 2;
  int* token_list = (int*)ws;        ws += (size_t)NEXP * N_TOK * 4;
  int* topk_idx = (int*)ws;          ws += (size_t)N_TOK * 4;
  float* topk_w0 = (float*)ws;       ws += (size_t)N_TOK * 4;
  int* gcount = (int*)ws;

  k_prep<<<dim3(4096), dim3(256), 0, stream>>>(x, Wr, br, We, xb, WeT, topk_idx, topk_w0, gcount);
  k_build_lists<<<dim3(N_TOK / 256), dim3(256), 0, stream>>>(topk_idx, gcount, token_list);
  // worst-case tile count: sum_e ceil(cnt_e/128)*8 <= (128+8)*8 = 1088
  k_moe_gemm<<<dim3(NWG), dim3(256), 0, stream>>>(xb, WeT, gcount, token_list, hbuf);
  k_combine<<<dim3(N_TOK / 2), dim3(256), 0, stream>>>(hbuf, topk_idx, topk_w0, be, out);
}